// Round 14
// baseline (315.283 us; speedup 1.0000x reference)
//
#include <hip/hip_runtime.h>
#include <hip/hip_bf16.h>

#define N_NODES 100000
#define N_EDGES 1600000
#define D_IN    256
#define D_OUT_T 512      // 8 heads * 64, concatenated
#define MPAD    100096   // 782 * 128

#define BM 128
#define BN 128
#define BK 64

#define NB_H2B 25000     // N_NODES*(D_IN/4)/256
#define NB_WCT 512       // 8*256*64/256
#define NB_DEG 6250      // N_EDGES/256

#define NPART 8
#define ROWS_PER_PART (N_NODES / NPART)   // 12500
#define FILL_BLOCKS 2048                  // 256 blocks per partition

typedef __attribute__((ext_vector_type(4))) float f32x4;
typedef __attribute__((ext_vector_type(8))) short bf16x8;
typedef __attribute__((ext_vector_type(4))) unsigned short u16x4;
typedef __attribute__((ext_vector_type(8))) unsigned short u16x8;

__device__ __forceinline__ float bf2f(unsigned short u) {
    union { unsigned int i; float f; } x; x.i = ((unsigned int)u) << 16; return x.f;
}
__device__ __forceinline__ unsigned short f2bf(float f) {
    union { float f; unsigned int i; } x; x.f = f;
    unsigned int i = x.i;
    return (unsigned short)((i + 0x7FFFu + ((i >> 16) & 1u)) >> 16);  // RNE
}

// ---------------- degree + rank ONLY (critical path to scan) ------------------
// rank[i] = atomicAdd return = within-row rank (r7 insight -> atomic-free fill).
__global__ __launch_bounds__(256) void k_deg(const int* __restrict__ erow,
                                             int* __restrict__ deg,
                                             int* __restrict__ rank) {
    int i = blockIdx.x * 256 + threadIdx.x;
    if (i < N_EDGES) rank[i] = atomicAdd(&deg[erow[i]], 1);
}

// ---------------- ONE-kernel segment allocation (atomic base reservation) -----
__global__ __launch_bounds__(256) void k_scan(const int* __restrict__ deg,
                                              int* __restrict__ start,
                                              int* __restrict__ gcnt) {
    __shared__ int sm[256];
    __shared__ int sbase;
    int t = threadIdx.x, i = blockIdx.x * 256 + t;
    int v = (i < N_NODES) ? deg[i] : 0;
    sm[t] = v; __syncthreads();
    #pragma unroll
    for (int o = 1; o < 256; o <<= 1) {
        int x = (t >= o) ? sm[t - o] : 0;
        __syncthreads();
        sm[t] += x;
        __syncthreads();
    }
    if (t == 255) sbase = atomicAdd(gcnt, sm[255]);
    __syncthreads();
    if (i < N_NODES) start[i] = sbase + sm[t] - v;
}

// ---------------- FUSED: CSR fill | h->bf16 | W->WcT --------------------------
// Blocks 0..2047: atomic-free fill (pos = start[r]+rank[i]), partition =
// blockIdx&7 (XCD affinity, r2/r6 write-amp lesson). Blocks 2048+: h2b
// streaming + WcT transpose overlap fill's latency-bound scatter.
__global__ __launch_bounds__(256) void k_fillpre(const int* __restrict__ erow,
                                                 const int* __restrict__ ecol,
                                                 const int* __restrict__ rank,
                                                 const int* __restrict__ start,
                                                 int* __restrict__ colidx,
                                                 const float* __restrict__ h,
                                                 unsigned short* __restrict__ hb,
                                                 const float* __restrict__ W,
                                                 unsigned short* __restrict__ WcT,
                                                 int do_hb) {
    int b = blockIdx.x;
    if (b < FILL_BLOCKS) {
        const int part = b & (NPART - 1);
        const int bi   = b >> 3;
        const int lo = part * ROWS_PER_PART;
        const int hi = lo + ROWS_PER_PART;
        const int stride = (FILL_BLOCKS / NPART) * 256;
        for (int i = bi * 256 + threadIdx.x; i < N_EDGES; i += stride) {
            int r = erow[i];
            if (r >= lo && r < hi)
                colidx[start[r] + rank[i]] = ecol[i];
        }
    } else if (b < FILL_BLOCKS + NB_H2B) {
        if (!do_hb) return;
        int i = (b - FILL_BLOCKS) * 256 + threadIdx.x;   // 6.4M float4 groups
        f32x4 v = ((const f32x4*)h)[i];
        u16x4 o; o.x = f2bf(v.x); o.y = f2bf(v.y); o.z = f2bf(v.z); o.w = f2bf(v.w);
        ((u16x4*)hb)[i] = o;
    } else {
        int t = (b - FILL_BLOCKS - NB_H2B) * 256 + threadIdx.x;  // 131072
        int hh = t >> 14;
        int rem = t & 16383;
        int d = rem >> 6;
        int j = rem & 63;
        WcT[(size_t)(hh * 64 + j) * 256 + d] = f2bf(W[t]);
    }
}

// ---------------- aggregation: one wave per node, PAIRED half-wave gather -----
// r12-proven (114us): two edges per wave-load. Lanes 0-31 gather row c_even at
// 16 B/lane (bf16x8), lanes 32-63 row c_odd; __shfl_xor(32) combines; lanes
// 0-31 store 16 B. 8/4/2/1-pair chunking keeps 8-deep load chains.
// r4/r11/r12 lessons: 16-deep, persistence, and issue-rate changes all null or
// regressed — this is the gather-equilibrium floor (~7.2 TB/s delivered).
template <bool BF16SRC>
__global__ __launch_bounds__(256) void k_agg(const void* __restrict__ src,
                                             const int* __restrict__ start,
                                             const int* __restrict__ deg,
                                             const int* __restrict__ colidx,
                                             unsigned short* __restrict__ hagg) {
    int wid = blockIdx.x * 4 + (threadIdx.x >> 6);
    int lane = threadIdx.x & 63;
    if (wid >= N_NODES) return;
    int s = start[wid];
    int d = deg[wid];
    int e = s + d;

    if constexpr (BF16SRC) {
        const unsigned short* hb = (const unsigned short*)src;
        const int half = lane >> 5;       // which edge of the pair
        const int sub  = lane & 31;       // d-chunk: elements [sub*8, sub*8+8)
        float acc[8] = {};
        int p = s;

        auto pairs = [&](int np) {        // process np pairs from p
            #pragma unroll 8
            for (int k = 0; k < np; ++k) {
                int c0 = colidx[p + 2 * k];
                int c1 = colidx[p + 2 * k + 1];
                int c = half ? c1 : c0;
                bf16x8 v = *(const bf16x8*)(hb + ((size_t)c << 8) + sub * 8);
                #pragma unroll
                for (int j = 0; j < 8; ++j)
                    acc[j] += bf2f(((unsigned short)v[j]));
            }
        };
        for (; p + 16 <= e; p += 16) pairs(8);
        if (p + 8 <= e) { pairs(4); p += 8; }
        if (p + 4 <= e) { pairs(2); p += 4; }
        if (p + 2 <= e) { pairs(1); p += 2; }
        if (p < e) {                       // odd tail: half0 adds
            int c = colidx[p];
            bf16x8 v = *(const bf16x8*)(hb + ((size_t)c << 8) + sub * 8);
            if (half == 0) {
                #pragma unroll
                for (int j = 0; j < 8; ++j)
                    acc[j] += bf2f(((unsigned short)v[j]));
            }
        }
        float inv = (d > 0) ? 1.0f / (float)d : 0.0f;
        u16x8 o;
        #pragma unroll
        for (int j = 0; j < 8; ++j) {
            float tot = acc[j] + __shfl_xor(acc[j], 32);
            o[j] = f2bf(tot * inv);
        }
        if (half == 0)
            *(u16x8*)(hagg + ((size_t)wid << 8) + sub * 8) = o;
    } else {
        // fp32 fallback (ws too small): full-wave 8-deep path
        const float* hf = (const float*)src;
        f32x4 acc[8] = {};
        int p = s;
        for (; p + 8 <= e; p += 8) {
            int c[8];
            #pragma unroll
            for (int j = 0; j < 8; ++j) c[j] = colidx[p + j];
            f32x4 v[8];
            #pragma unroll
            for (int j = 0; j < 8; ++j)
                v[j] = *((const f32x4*)(hf + ((size_t)c[j] << 8)) + lane);
            #pragma unroll
            for (int j = 0; j < 8; ++j) acc[j] += v[j];
        }
        for (; p < e; ++p)
            acc[0] += *((const f32x4*)(hf + ((size_t)colidx[p] << 8)) + lane);
        #pragma unroll
        for (int j = 4; j < 8; ++j) acc[j - 4] += acc[j];
        acc[0] += acc[2]; acc[1] += acc[3]; acc[0] += acc[1];
        float inv = (d > 0) ? 1.0f / (float)d : 0.0f;
        u16x4 o;
        o.x = f2bf(acc[0].x * inv); o.y = f2bf(acc[0].y * inv);
        o.z = f2bf(acc[0].z * inv); o.w = f2bf(acc[0].w * inv);
        *((u16x4*)(hagg + ((size_t)wid << 8)) + lane) = o;
    }
}

// ---------------- GEMM: C[M x 512] = hagg[M x 256] * Wc[256 x 512] ----------------
// r14: T3-minimum DOUBLE-BUFFERED staging (guide §5.5 T3 recipe). Prologue
// stages buf0; each step issues STAGE(buf^1, t+1) BEFORE computing buf[cur],
// so next-tile global_load_lds fly under the MFMAs; ONE __syncthreads per step
// (implicit vmcnt(0) publishes the prefetch; also halves barrier count).
// Buffer safety: buf written at step t was last read at t-1, sealed by t-1's
// barrier. LDS 2x(16+16)KB = 64KB -> still 2 blocks/CU at (256,2).
// Keeps: r3 geometry, r10 operand-swap (C^T regs -> 16 f32x4 stores),
// 16B-chunk XOR swizzle both-sides, XCD-chunk grid swizzle.
__global__ __launch_bounds__(256, 2) void k_gemm(const unsigned short* __restrict__ A,
                                                 const unsigned short* __restrict__ B,
                                                 float* __restrict__ C, int M) {
    __shared__ __align__(16) unsigned short As[2][BM * BK];
    __shared__ __align__(16) unsigned short Bs[2][BN * BK];
    const int orig = blockIdx.x;                   // 3128 = 782*4, 3128%8==0
    const int wgid = (orig & 7) * (3128 / 8) + (orig >> 3);
    const int M0 = (wgid >> 2) * BM;
    const int N0 = (wgid & 3) * BN;
    const int tid  = threadIdx.x;
    const int wave = tid >> 6;
    const int lane = tid & 63;
    const int wm = (wave >> 1) * 64;
    const int wn = (wave & 1) * 64;

    f32x4 acc[4][4] = {};

    auto stage = [&](int buf, int kk) {
        #pragma unroll
        for (int i = 0; i < 4; ++i) {  // A tile: 128 rows x 64 k
            int rbase = i * 32 + wave * 8;
            int r = rbase + (lane >> 3);
            int gc = (lane & 7) ^ (r & 7);  // inverse-swizzled source chunk
            const unsigned short* g = A + (size_t)(M0 + r) * D_IN + kk + gc * 8;
            __builtin_amdgcn_global_load_lds(
                (const __attribute__((address_space(1))) void*)g,
                (__attribute__((address_space(3))) void*)(As[buf] + rbase * 64), 16, 0, 0);
        }
        #pragma unroll
        for (int i = 0; i < 4; ++i) {  // B tile: 128 cols x 64 k
            int rbase = i * 32 + wave * 8;
            int r = rbase + (lane >> 3);
            int gc = (lane & 7) ^ (r & 7);
            const unsigned short* g = B + (size_t)(N0 + r) * D_IN + kk + gc * 8;
            __builtin_amdgcn_global_load_lds(
                (const __attribute__((address_space(1))) void*)g,
                (__attribute__((address_space(3))) void*)(Bs[buf] + rbase * 64), 16, 0, 0);
        }
    };

    stage(0, 0);
    __syncthreads();               // implicit vmcnt(0): buf0 ready
    int cur = 0;

    #pragma unroll
    for (int step = 0; step < 4; ++step) {
        if (step < 3) stage(cur ^ 1, (step + 1) * BK);  // prefetch under MFMA
        #pragma unroll
        for (int ks = 0; ks < 2; ++ks) {
            bf16x8 a[4], b[4];
            #pragma unroll
            for (int m = 0; m < 4; ++m) {
                int r = wm + m * 16 + (lane & 15);
                int lc = (ks * 4 + (lane >> 4)) ^ (r & 7);  // swizzled read chunk
                a[m] = *(const bf16x8*)(As[cur] + r * 64 + lc * 8);
            }
            #pragma unroll
            for (int n = 0; n < 4; ++n) {
                int c = wn + n * 16 + (lane & 15);
                int lc = (ks * 4 + (lane >> 4)) ^ (c & 7);
                b[n] = *(const bf16x8*)(Bs[cur] + c * 64 + lc * 8);
            }
            #pragma unroll
            for (int m = 0; m < 4; ++m)
                #pragma unroll
                for (int n = 0; n < 4; ++n)
                    acc[m][n] = __builtin_amdgcn_mfma_f32_16x16x32_bf16(
                        b[n], a[m], acc[m][n], 0, 0, 0);   // SWAPPED -> C^T regs
        }
        if (step < 3) {
            __syncthreads();       // drains prefetch + seals reads of cur
            cur ^= 1;
        }
    }

    // Swapped C/D layout: M = lane&15, N = (lane>>4)*4 + reg -> f32x4 store.
    #pragma unroll
    for (int m = 0; m < 4; ++m) {
        int row = M0 + wm + m * 16 + (lane & 15);
        if (row < M) {
            #pragma unroll
            for (int n = 0; n < 4; ++n) {
                int col = N0 + wn + n * 16 + (lane >> 4) * 4;
                *(f32x4*)(C + (size_t)row * D_OUT_T + col) = acc[m][n];
            }
        }
    }
}

extern "C" void kernel_launch(void* const* d_in, const int* in_sizes, int n_in,
                              void* d_out, int out_size, void* d_ws, size_t ws_size,
                              hipStream_t stream) {
    const float* h  = (const float*)d_in[0];
    const float* W  = (const float*)d_in[1];
    const int* erow = (const int*)d_in[2];
    const int* ecol = erow + N_EDGES;
    float* out = (float*)d_out;

    char* base = (char*)d_ws;
    size_t off = 0;
    auto alloc = [&](size_t b) {
        char* p = base + off;
        off += (b + 255) & ~(size_t)255;
        return p;
    };
    int* deg    = (int*)alloc((N_NODES + 1) * sizeof(int));  // [N] = global cursor
    int* start  = (int*)alloc(N_NODES * sizeof(int));
    int* rank   = (int*)alloc((size_t)N_EDGES * sizeof(int));
    int* colidx = (int*)alloc((size_t)N_EDGES * sizeof(int));
    unsigned short* WcT  = (unsigned short*)alloc((size_t)D_OUT_T * D_IN * 2);
    unsigned short* hagg = (unsigned short*)alloc((size_t)MPAD * D_IN * 2);
    unsigned short* hb   = (unsigned short*)alloc((size_t)N_NODES * D_IN * 2);
    bool use_hb = (off <= ws_size);  // fall back to fp32 gather if ws too small

    hipMemsetAsync(deg, 0, (N_NODES + 1) * sizeof(int), stream);

    k_deg<<<NB_DEG, 256, 0, stream>>>(erow, deg, rank);

    const int NB = (N_NODES + 255) / 256;  // 391
    k_scan<<<NB, 256, 0, stream>>>(deg, start, deg + N_NODES);

    k_fillpre<<<FILL_BLOCKS + NB_H2B + NB_WCT, 256, 0, stream>>>(
        erow, ecol, rank, start, colidx, h, hb, W, WcT, use_hb ? 1 : 0);

    if (use_hb)
        k_agg<true><<<(N_NODES + 3) / 4, 256, 0, stream>>>(hb, start, deg, colidx, hagg);
    else
        k_agg<false><<<(N_NODES + 3) / 4, 256, 0, stream>>>(h, start, deg, colidx, hagg);

    k_gemm<<<MPAD / BM * 4, 256, 0, stream>>>(hagg, WcT, out, N_NODES);
}

// Round 15
// 262.344 us; speedup vs baseline: 1.2018x; 1.2018x over previous
//
#include <hip/hip_runtime.h>
#include <hip/hip_bf16.h>

#define N_NODES 100000
#define N_EDGES 1600000
#define D_IN    256
#define D_OUT_T 512      // 8 heads * 64, concatenated
#define MPAD    100096   // 782 * 128

#define BM 128
#define BN 128
#define BK 64

#define NB_H8  25000     // 4 rows per block (1 wave/row)
#define NB_WCT 512       // 8*256*64/256
#define NB_DEG 6250      // N_EDGES/256

#define NPART 8
#define ROWS_PER_PART (N_NODES / NPART)   // 12500
#define FILL_BLOCKS 2048                  // 256 blocks per partition

typedef __attribute__((ext_vector_type(4))) float f32x4;
typedef __attribute__((ext_vector_type(8))) short bf16x8;
typedef __attribute__((ext_vector_type(4))) unsigned short u16x4;
typedef __attribute__((ext_vector_type(8))) unsigned short u16x8;
typedef __attribute__((ext_vector_type(2))) int i32x2;

__device__ __forceinline__ float bf2f(unsigned short u) {
    union { unsigned int i; float f; } x; x.i = ((unsigned int)u) << 16; return x.f;
}
__device__ __forceinline__ unsigned short f2bf(float f) {
    union { float f; unsigned int i; } x; x.f = f;
    unsigned int i = x.i;
    return (unsigned short)((i + 0x7FFFu + ((i >> 16) & 1u)) >> 16);  // RNE
}

// ---------------- degree + rank ONLY (critical path to scan) ------------------
// rank[i] = atomicAdd return = within-row rank (r7 insight -> atomic-free fill).
__global__ __launch_bounds__(256) void k_deg(const int* __restrict__ erow,
                                             int* __restrict__ deg,
                                             int* __restrict__ rank) {
    int i = blockIdx.x * 256 + threadIdx.x;
    if (i < N_EDGES) rank[i] = atomicAdd(&deg[erow[i]], 1);
}

// ---------------- ONE-kernel segment allocation (atomic base reservation) -----
__global__ __launch_bounds__(256) void k_scan(const int* __restrict__ deg,
                                              int* __restrict__ start,
                                              int* __restrict__ gcnt) {
    __shared__ int sm[256];
    __shared__ int sbase;
    int t = threadIdx.x, i = blockIdx.x * 256 + t;
    int v = (i < N_NODES) ? deg[i] : 0;
    sm[t] = v; __syncthreads();
    #pragma unroll
    for (int o = 1; o < 256; o <<= 1) {
        int x = (t >= o) ? sm[t - o] : 0;
        __syncthreads();
        sm[t] += x;
        __syncthreads();
    }
    if (t == 255) sbase = atomicAdd(gcnt, sm[255]);
    __syncthreads();
    if (i < N_NODES) start[i] = sbase + sm[t] - v;
}

// ---------------- FUSED: CSR fill | h->int8 quant | W->WcT --------------------
// Blocks 0..2047: atomic-free fill (pos = start[r]+rank[i]), partition =
// blockIdx&7 (XCD affinity, r2/r6 write-amp lesson).
// Blocks 2048..2048+25000: r15 INT8 row quantization — one wave per h row:
// m = max|row| (shfl reduce), scale[row] = m/127, q = clamp(rint(h*127/m)),
// 4 int8 packed per lane -> h8 row = 256 B (halves k_agg's gather traffic;
// working set 51MB -> 25.6MB, fully LLC-resident).
// Last 512 blocks: WcT transpose.
__global__ __launch_bounds__(256) void k_fillpre(const int* __restrict__ erow,
                                                 const int* __restrict__ ecol,
                                                 const int* __restrict__ rank,
                                                 const int* __restrict__ start,
                                                 int* __restrict__ colidx,
                                                 const float* __restrict__ h,
                                                 int* __restrict__ h8,
                                                 float* __restrict__ scale,
                                                 const float* __restrict__ W,
                                                 unsigned short* __restrict__ WcT,
                                                 int do_h8) {
    int b = blockIdx.x;
    if (b < FILL_BLOCKS) {
        const int part = b & (NPART - 1);
        const int bi   = b >> 3;
        const int lo = part * ROWS_PER_PART;
        const int hi = lo + ROWS_PER_PART;
        const int stride = (FILL_BLOCKS / NPART) * 256;
        for (int i = bi * 256 + threadIdx.x; i < N_EDGES; i += stride) {
            int r = erow[i];
            if (r >= lo && r < hi)
                colidx[start[r] + rank[i]] = ecol[i];
        }
    } else if (b < FILL_BLOCKS + NB_H8) {
        if (!do_h8) return;
        int row = (b - FILL_BLOCKS) * 4 + (threadIdx.x >> 6);
        int l = threadIdx.x & 63;
        f32x4 v = ((const f32x4*)h)[(size_t)row * 64 + l];
        float m = fmaxf(fmaxf(fabsf(v.x), fabsf(v.y)), fmaxf(fabsf(v.z), fabsf(v.w)));
        #pragma unroll
        for (int o = 32; o; o >>= 1) m = fmaxf(m, __shfl_xor(m, o));
        float isc = (m > 0.f) ? 127.0f / m : 0.0f;
        int qx = min(127, max(-127, (int)rintf(v.x * isc)));
        int qy = min(127, max(-127, (int)rintf(v.y * isc)));
        int qz = min(127, max(-127, (int)rintf(v.z * isc)));
        int qw = min(127, max(-127, (int)rintf(v.w * isc)));
        h8[(size_t)row * 64 + l] =
            (qx & 0xFF) | ((qy & 0xFF) << 8) | ((qz & 0xFF) << 16) | ((qw & 0xFF) << 24);
        if (l == 0) scale[row] = m * (1.0f / 127.0f);
    } else {
        int t = (b - FILL_BLOCKS - NB_H8) * 256 + threadIdx.x;  // 131072
        int hh = t >> 14;
        int rem = t & 16383;
        int d = rem >> 6;
        int j = rem & 63;
        WcT[(size_t)(hh * 64 + j) * 256 + d] = f2bf(W[t]);
    }
}

// ---------------- aggregation: one wave per node, PAIRED int8 gather ----------
// r15: gather int8 rows (256 B each) — half the traffic of the bf16 version
// that plateaued at 114us across r10-r12 (traffic-bound; depth/persistence/
// issue-rate all proven null). r12 pairing kept: lanes 0-31 row c_even,
// lanes 32-63 row c_odd, 8 B/lane (i32x2 = 8 int8 = elems [sub*8,sub*8+8));
// acc[j] += scale[c] * (float)q[j]; __shfl_xor(32) combines; lanes 0-31 store.
template <bool I8SRC>
__global__ __launch_bounds__(256) void k_agg(const void* __restrict__ src,
                                             const float* __restrict__ scale,
                                             const int* __restrict__ start,
                                             const int* __restrict__ deg,
                                             const int* __restrict__ colidx,
                                             unsigned short* __restrict__ hagg) {
    int wid = blockIdx.x * 4 + (threadIdx.x >> 6);
    int lane = threadIdx.x & 63;
    if (wid >= N_NODES) return;
    int s = start[wid];
    int d = deg[wid];
    int e = s + d;

    if constexpr (I8SRC) {
        const signed char* h8 = (const signed char*)src;
        const int half = lane >> 5;       // which edge of the pair
        const int sub  = lane & 31;       // d-chunk: elems [sub*8, sub*8+8)
        float acc[8] = {};
        int p = s;

        auto pairs = [&](int np) {        // process np pairs from p
            #pragma unroll 8
            for (int k = 0; k < np; ++k) {
                int c0 = colidx[p + 2 * k];
                int c1 = colidx[p + 2 * k + 1];
                int c = half ? c1 : c0;
                float sc = scale[c];
                i32x2 w = *((const i32x2*)(h8 + ((size_t)c << 8)) + sub);
                #pragma unroll
                for (int j = 0; j < 4; ++j)
                    acc[j] += sc * (float)((signed char)(w.x >> (8 * j)));
                #pragma unroll
                for (int j = 0; j < 4; ++j)
                    acc[4 + j] += sc * (float)((signed char)(w.y >> (8 * j)));
            }
        };
        for (; p + 16 <= e; p += 16) pairs(8);
        if (p + 8 <= e) { pairs(4); p += 8; }
        if (p + 4 <= e) { pairs(2); p += 4; }
        if (p + 2 <= e) { pairs(1); p += 2; }
        if (p < e) {                       // odd tail: half0 adds
            int c = colidx[p];
            float sc = scale[c];
            i32x2 w = *((const i32x2*)(h8 + ((size_t)c << 8)) + sub);
            if (half == 0) {
                #pragma unroll
                for (int j = 0; j < 4; ++j)
                    acc[j] += sc * (float)((signed char)(w.x >> (8 * j)));
                #pragma unroll
                for (int j = 0; j < 4; ++j)
                    acc[4 + j] += sc * (float)((signed char)(w.y >> (8 * j)));
            }
        }
        float inv = (d > 0) ? 1.0f / (float)d : 0.0f;
        u16x8 o;
        #pragma unroll
        for (int j = 0; j < 8; ++j) {
            float tot = acc[j] + __shfl_xor(acc[j], 32);
            o[j] = f2bf(tot * inv);
        }
        if (half == 0)
            *(u16x8*)(hagg + ((size_t)wid << 8) + sub * 8) = o;
    } else {
        // fp32 fallback (ws too small): full-wave 8-deep path
        const float* hf = (const float*)src;
        f32x4 acc[8] = {};
        int p = s;
        for (; p + 8 <= e; p += 8) {
            int c[8];
            #pragma unroll
            for (int j = 0; j < 8; ++j) c[j] = colidx[p + j];
            f32x4 v[8];
            #pragma unroll
            for (int j = 0; j < 8; ++j)
                v[j] = *((const f32x4*)(hf + ((size_t)c[j] << 8)) + lane);
            #pragma unroll
            for (int j = 0; j < 8; ++j) acc[j] += v[j];
        }
        for (; p < e; ++p)
            acc[0] += *((const f32x4*)(hf + ((size_t)colidx[p] << 8)) + lane);
        #pragma unroll
        for (int j = 4; j < 8; ++j) acc[j - 4] += acc[j];
        acc[0] += acc[2]; acc[1] += acc[3]; acc[0] += acc[1];
        float inv = (d > 0) ? 1.0f / (float)d : 0.0f;
        u16x4 o;
        o.x = f2bf(acc[0].x * inv); o.y = f2bf(acc[0].y * inv);
        o.z = f2bf(acc[0].z * inv); o.w = f2bf(acc[0].w * inv);
        *((u16x4*)(hagg + ((size_t)wid << 8)) + lane) = o;
    }
}

// ---------------- GEMM: C[M x 512] = hagg[M x 256] * Wc[256 x 512] ----------------
// r13-proven version (r14 double-buffer regressed 308->315 — reverted).
// r3 geometry + r10 operand-swapped MFMA (C^T regs -> 16 f32x4 stores),
// __launch_bounds__(256,3). 128x128 tile, 4 waves (2x2), wave 64x64, BK=64.
// LDS [rows][64] with 16B-chunk XOR swizzle (chunk ^= row&7), both-sides.
// 1D grid with XCD-chunk swizzle: 4 N-blocks of an A panel share an XCD.
__global__ __launch_bounds__(256, 3) void k_gemm(const unsigned short* __restrict__ A,
                                                 const unsigned short* __restrict__ B,
                                                 float* __restrict__ C, int M) {
    __shared__ __align__(16) unsigned short As[BM * BK];
    __shared__ __align__(16) unsigned short Bs[BN * BK];
    const int orig = blockIdx.x;                   // 3128 = 782*4, 3128%8==0
    const int wgid = (orig & 7) * (3128 / 8) + (orig >> 3);
    const int M0 = (wgid >> 2) * BM;
    const int N0 = (wgid & 3) * BN;
    const int tid  = threadIdx.x;
    const int wave = tid >> 6;
    const int lane = tid & 63;
    const int wm = (wave >> 1) * 64;
    const int wn = (wave & 1) * 64;

    f32x4 acc[4][4] = {};

    for (int kk = 0; kk < D_IN; kk += BK) {
        __syncthreads();  // previous-iteration LDS reads done before overwrite
        #pragma unroll
        for (int i = 0; i < 4; ++i) {  // stage A tile: 128 rows x 64 k
            int rbase = i * 32 + wave * 8;
            int r = rbase + (lane >> 3);
            int gc = (lane & 7) ^ (r & 7);  // inverse-swizzled source chunk
            const unsigned short* g = A + (size_t)(M0 + r) * D_IN + kk + gc * 8;
            __builtin_amdgcn_global_load_lds(
                (const __attribute__((address_space(1))) void*)g,
                (__attribute__((address_space(3))) void*)(As + rbase * 64), 16, 0, 0);
        }
        #pragma unroll
        for (int i = 0; i < 4; ++i) {  // stage B tile: 128 cols x 64 k
            int rbase = i * 32 + wave * 8;
            int r = rbase + (lane >> 3);
            int gc = (lane & 7) ^ (r & 7);
            const unsigned short* g = B + (size_t)(N0 + r) * D_IN + kk + gc * 8;
            __builtin_amdgcn_global_load_lds(
                (const __attribute__((address_space(1))) void*)g,
                (__attribute__((address_space(3))) void*)(Bs + rbase * 64), 16, 0, 0);
        }
        __syncthreads();

        #pragma unroll
        for (int ks = 0; ks < 2; ++ks) {
            bf16x8 a[4], b[4];
            #pragma unroll
            for (int m = 0; m < 4; ++m) {
                int r = wm + m * 16 + (lane & 15);
                int lc = (ks * 4 + (lane >> 4)) ^ (r & 7);  // swizzled read chunk
                a[m] = *(const bf16x8*)(As + r * 64 + lc * 8);
            }
            #pragma unroll
            for (int n = 0; n < 4; ++n) {
                int c = wn + n * 16 + (lane & 15);
                int lc = (ks * 4 + (lane >> 4)) ^ (c & 7);
                b[n] = *(const bf16x8*)(Bs + c * 64 + lc * 8);
            }
            #pragma unroll
            for (int m = 0; m < 4; ++m)
                #pragma unroll
                for (int n = 0; n < 4; ++n)
                    acc[m][n] = __builtin_amdgcn_mfma_f32_16x16x32_bf16(
                        b[n], a[m], acc[m][n], 0, 0, 0);   // SWAPPED -> C^T regs
        }
    }

    // Swapped C/D layout: M = lane&15, N = (lane>>4)*4 + reg -> f32x4 store.
    #pragma unroll
    for (int m = 0; m < 4; ++m) {
        int row = M0 + wm + m * 16 + (lane & 15);
        if (row < M) {
            #pragma unroll
            for (int n = 0; n < 4; ++n) {
                int col = N0 + wn + n * 16 + (lane >> 4) * 4;
                *(f32x4*)(C + (size_t)row * D_OUT_T + col) = acc[m][n];
            }
        }
    }
}

extern "C" void kernel_launch(void* const* d_in, const int* in_sizes, int n_in,
                              void* d_out, int out_size, void* d_ws, size_t ws_size,
                              hipStream_t stream) {
    const float* h  = (const float*)d_in[0];
    const float* W  = (const float*)d_in[1];
    const int* erow = (const int*)d_in[2];
    const int* ecol = erow + N_EDGES;
    float* out = (float*)d_out;

    char* base = (char*)d_ws;
    size_t off = 0;
    auto alloc = [&](size_t b) {
        char* p = base + off;
        off += (b + 255) & ~(size_t)255;
        return p;
    };
    int* deg    = (int*)alloc((N_NODES + 1) * sizeof(int));  // [N] = global cursor
    int* start  = (int*)alloc(N_NODES * sizeof(int));
    int* rank   = (int*)alloc((size_t)N_EDGES * sizeof(int));
    int* colidx = (int*)alloc((size_t)N_EDGES * sizeof(int));
    unsigned short* WcT  = (unsigned short*)alloc((size_t)D_OUT_T * D_IN * 2);
    unsigned short* hagg = (unsigned short*)alloc((size_t)MPAD * D_IN * 2);
    int*   h8    = (int*)alloc((size_t)N_NODES * 64 * sizeof(int));  // 25.6MB
    float* scale = (float*)alloc((size_t)N_NODES * sizeof(float));
    bool use_h8 = (off <= ws_size);  // fall back to fp32 gather if ws too small

    hipMemsetAsync(deg, 0, (N_NODES + 1) * sizeof(int), stream);

    k_deg<<<NB_DEG, 256, 0, stream>>>(erow, deg, rank);

    const int NB = (N_NODES + 255) / 256;  // 391
    k_scan<<<NB, 256, 0, stream>>>(deg, start, deg + N_NODES);

    k_fillpre<<<FILL_BLOCKS + NB_H8 + NB_WCT, 256, 0, stream>>>(
        erow, ecol, rank, start, colidx, h, h8, scale, W, WcT, use_h8 ? 1 : 0);

    if (use_h8)
        k_agg<true><<<(N_NODES + 3) / 4, 256, 0, stream>>>(
            h8, scale, start, deg, colidx, hagg);
    else
        k_agg<false><<<(N_NODES + 3) / 4, 256, 0, stream>>>(
            h, scale, start, deg, colidx, hagg);

    k_gemm<<<MPAD / BM * 4, 256, 0, stream>>>(hagg, WcT, out, N_NODES);
}

// Round 16
// 257.980 us; speedup vs baseline: 1.2221x; 1.0169x over previous
//
#include <hip/hip_runtime.h>
#include <hip/hip_bf16.h>

#define N_NODES 100000
#define N_EDGES 1600000
#define D_IN    256
#define D_OUT_T 512      // 8 heads * 64, concatenated
#define MPAD    100096   // 782 * 128

#define BM 128
#define BN 128
#define BK 64

#define NB_H8  25000     // 4 rows per block (1 wave/row)
#define NB_WCT 512       // 8*256*64/256
#define NB_DEG 6250      // N_EDGES/256

#define NPART 8
#define ROWS_PER_PART (N_NODES / NPART)   // 12500
#define FILL_BLOCKS 2048                  // 256 blocks per partition

typedef __attribute__((ext_vector_type(4))) float f32x4;
typedef __attribute__((ext_vector_type(8))) short bf16x8;
typedef __attribute__((ext_vector_type(4))) unsigned short u16x4;
typedef __attribute__((ext_vector_type(8))) unsigned short u16x8;
typedef __attribute__((ext_vector_type(2))) int i32x2;

__device__ __forceinline__ float bf2f(unsigned short u) {
    union { unsigned int i; float f; } x; x.i = ((unsigned int)u) << 16; return x.f;
}
__device__ __forceinline__ unsigned short f2bf(float f) {
    union { float f; unsigned int i; } x; x.f = f;
    unsigned int i = x.i;
    return (unsigned short)((i + 0x7FFFu + ((i >> 16) & 1u)) >> 16);  // RNE
}

// ---------------- FUSED front: deg+rank | h->int8 quant | W->WcT --------------
// r16: quant/wct moved OFF the post-scan serial path. deg is latency-bound
// (2% VALU) so quant's 100MB streaming coexists freely in the same dispatch.
// Blocks [0,6250): rank[i] = atomicAdd(&deg[erow[i]],1) (r7 atomic-free-fill).
// Blocks [6250, 6250+25000): int8 row quant — one wave per h row: m = max|row|
// (shfl), scale[row]=m/127, q=clamp(rint(h*127/m)), 4 int8/lane -> 256B rows
// (r15: halved gather traffic, 308->262).
// Last 512: WcT[h*64+j][d] = W[h][d][j].
__global__ __launch_bounds__(256) void k_pre2(const int* __restrict__ erow,
                                              int* __restrict__ deg,
                                              int* __restrict__ rank,
                                              const float* __restrict__ h,
                                              int* __restrict__ h8,
                                              float* __restrict__ scale,
                                              const float* __restrict__ W,
                                              unsigned short* __restrict__ WcT,
                                              int do_h8) {
    int b = blockIdx.x;
    if (b < NB_DEG) {
        int i = b * 256 + threadIdx.x;
        if (i < N_EDGES) rank[i] = atomicAdd(&deg[erow[i]], 1);
    } else if (b < NB_DEG + NB_H8) {
        if (!do_h8) return;
        int row = (b - NB_DEG) * 4 + (threadIdx.x >> 6);
        int l = threadIdx.x & 63;
        f32x4 v = ((const f32x4*)h)[(size_t)row * 64 + l];
        float m = fmaxf(fmaxf(fabsf(v.x), fabsf(v.y)), fmaxf(fabsf(v.z), fabsf(v.w)));
        #pragma unroll
        for (int o = 32; o; o >>= 1) m = fmaxf(m, __shfl_xor(m, o));
        float isc = (m > 0.f) ? 127.0f / m : 0.0f;
        int qx = min(127, max(-127, (int)rintf(v.x * isc)));
        int qy = min(127, max(-127, (int)rintf(v.y * isc)));
        int qz = min(127, max(-127, (int)rintf(v.z * isc)));
        int qw = min(127, max(-127, (int)rintf(v.w * isc)));
        h8[(size_t)row * 64 + l] =
            (qx & 0xFF) | ((qy & 0xFF) << 8) | ((qz & 0xFF) << 16) | ((qw & 0xFF) << 24);
        if (l == 0) scale[row] = m * (1.0f / 127.0f);
    } else {
        int t = (b - NB_DEG - NB_H8) * 256 + threadIdx.x;  // 131072
        int hh = t >> 14;
        int rem = t & 16383;
        int d = rem >> 6;
        int j = rem & 63;
        WcT[(size_t)(hh * 64 + j) * 256 + d] = f2bf(W[t]);
    }
}

// ---------------- ONE-kernel segment allocation (atomic base reservation) -----
__global__ __launch_bounds__(256) void k_scan(const int* __restrict__ deg,
                                              int* __restrict__ start,
                                              int* __restrict__ gcnt) {
    __shared__ int sm[256];
    __shared__ int sbase;
    int t = threadIdx.x, i = blockIdx.x * 256 + t;
    int v = (i < N_NODES) ? deg[i] : 0;
    sm[t] = v; __syncthreads();
    #pragma unroll
    for (int o = 1; o < 256; o <<= 1) {
        int x = (t >= o) ? sm[t - o] : 0;
        __syncthreads();
        sm[t] += x;
        __syncthreads();
    }
    if (t == 255) sbase = atomicAdd(gcnt, sm[255]);
    __syncthreads();
    if (i < N_NODES) start[i] = sbase + sm[t] - v;
}

// ---------------- CSR fill: ATOMIC-FREE, row-range partitioned (NPART=8) ------
// pos = start[r]+rank[i] unique -> plain store. Partition p = blockIdx&7 (XCD
// round-robin) -> colidx region written from one XCD -> full-line writebacks
// (r2/r6 write-amp lesson). Edge re-reads (passes 2..8) hit LLC.
__global__ __launch_bounds__(256) void k_fill(const int* __restrict__ erow,
                                              const int* __restrict__ ecol,
                                              const int* __restrict__ rank,
                                              const int* __restrict__ start,
                                              int* __restrict__ colidx) {
    const int part = blockIdx.x & (NPART - 1);
    const int bi   = blockIdx.x >> 3;
    const int lo = part * ROWS_PER_PART;
    const int hi = lo + ROWS_PER_PART;
    const int stride = (FILL_BLOCKS / NPART) * 256;
    for (int i = bi * 256 + threadIdx.x; i < N_EDGES; i += stride) {
        int r = erow[i];
        if (r >= lo && r < hi)
            colidx[start[r] + rank[i]] = ecol[i];
    }
}

// ---------------- aggregation: one wave per node, PAIRED int8 gather ----------
// r15-proven: int8 rows (256 B) — half the traffic of the bf16 version that
// plateaued at 114us (traffic-bound; depth/persistence/issue-rate all null).
// Lanes 0-31 row c_even, lanes 32-63 row c_odd, 8 B/lane (i32x2 = 8 int8);
// acc[j] += scale[c]*(float)q[j]; __shfl_xor(32) combines; lanes 0-31 store.
template <bool I8SRC>
__global__ __launch_bounds__(256) void k_agg(const void* __restrict__ src,
                                             const float* __restrict__ scale,
                                             const int* __restrict__ start,
                                             const int* __restrict__ deg,
                                             const int* __restrict__ colidx,
                                             unsigned short* __restrict__ hagg) {
    int wid = blockIdx.x * 4 + (threadIdx.x >> 6);
    int lane = threadIdx.x & 63;
    if (wid >= N_NODES) return;
    int s = start[wid];
    int d = deg[wid];
    int e = s + d;

    if constexpr (I8SRC) {
        const signed char* h8 = (const signed char*)src;
        const int half = lane >> 5;       // which edge of the pair
        const int sub  = lane & 31;       // d-chunk: elems [sub*8, sub*8+8)
        float acc[8] = {};
        int p = s;

        auto pairs = [&](int np) {        // process np pairs from p
            #pragma unroll 8
            for (int k = 0; k < np; ++k) {
                int c0 = colidx[p + 2 * k];
                int c1 = colidx[p + 2 * k + 1];
                int c = half ? c1 : c0;
                float sc = scale[c];
                i32x2 w = *((const i32x2*)(h8 + ((size_t)c << 8)) + sub);
                #pragma unroll
                for (int j = 0; j < 4; ++j)
                    acc[j] += sc * (float)((signed char)(w.x >> (8 * j)));
                #pragma unroll
                for (int j = 0; j < 4; ++j)
                    acc[4 + j] += sc * (float)((signed char)(w.y >> (8 * j)));
            }
        };
        for (; p + 16 <= e; p += 16) pairs(8);
        if (p + 8 <= e) { pairs(4); p += 8; }
        if (p + 4 <= e) { pairs(2); p += 4; }
        if (p + 2 <= e) { pairs(1); p += 2; }
        if (p < e) {                       // odd tail: half0 adds
            int c = colidx[p];
            float sc = scale[c];
            i32x2 w = *((const i32x2*)(h8 + ((size_t)c << 8)) + sub);
            if (half == 0) {
                #pragma unroll
                for (int j = 0; j < 4; ++j)
                    acc[j] += sc * (float)((signed char)(w.x >> (8 * j)));
                #pragma unroll
                for (int j = 0; j < 4; ++j)
                    acc[4 + j] += sc * (float)((signed char)(w.y >> (8 * j)));
            }
        }
        float inv = (d > 0) ? 1.0f / (float)d : 0.0f;
        u16x8 o;
        #pragma unroll
        for (int j = 0; j < 8; ++j) {
            float tot = acc[j] + __shfl_xor(acc[j], 32);
            o[j] = f2bf(tot * inv);
        }
        if (half == 0)
            *(u16x8*)(hagg + ((size_t)wid << 8) + sub * 8) = o;
    } else {
        // fp32 fallback (ws too small): full-wave 8-deep path
        const float* hf = (const float*)src;
        f32x4 acc[8] = {};
        int p = s;
        for (; p + 8 <= e; p += 8) {
            int c[8];
            #pragma unroll
            for (int j = 0; j < 8; ++j) c[j] = colidx[p + j];
            f32x4 v[8];
            #pragma unroll
            for (int j = 0; j < 8; ++j)
                v[j] = *((const f32x4*)(hf + ((size_t)c[j] << 8)) + lane);
            #pragma unroll
            for (int j = 0; j < 8; ++j) acc[j] += v[j];
        }
        for (; p < e; ++p)
            acc[0] += *((const f32x4*)(hf + ((size_t)colidx[p] << 8)) + lane);
        #pragma unroll
        for (int j = 4; j < 8; ++j) acc[j - 4] += acc[j];
        acc[0] += acc[2]; acc[1] += acc[3]; acc[0] += acc[1];
        float inv = (d > 0) ? 1.0f / (float)d : 0.0f;
        u16x4 o;
        o.x = f2bf(acc[0].x * inv); o.y = f2bf(acc[0].y * inv);
        o.z = f2bf(acc[0].z * inv); o.w = f2bf(acc[0].w * inv);
        *((u16x4*)(hagg + ((size_t)wid << 8)) + lane) = o;
    }
}

// ---------------- GEMM: C[M x 512] = hagg[M x 256] * Wc[256 x 512] ----------------
// r13-proven structure (r5/r9/r14 restructures all regressed). r3 geometry +
// r10 operand-swapped MFMA (C^T regs -> 16 f32x4 stores), (256,3).
// r16 change: NONTEMPORAL C stores — C is 205MB stream-once data; NT bypasses
// cache-allocate on the write path. 128x128 tile, 4 waves (2x2), wave 64x64,
// BK=64. LDS [rows][64], 16B-chunk XOR swizzle (chunk ^= row&7), both-sides.
// 1D grid with XCD-chunk swizzle: 4 N-blocks of an A panel share an XCD.
__global__ __launch_bounds__(256, 3) void k_gemm(const unsigned short* __restrict__ A,
                                                 const unsigned short* __restrict__ B,
                                                 float* __restrict__ C, int M) {
    __shared__ __align__(16) unsigned short As[BM * BK];
    __shared__ __align__(16) unsigned short Bs[BN * BK];
    const int orig = blockIdx.x;                   // 3128 = 782*4, 3128%8==0
    const int wgid = (orig & 7) * (3128 / 8) + (orig >> 3);
    const int M0 = (wgid >> 2) * BM;
    const int N0 = (wgid & 3) * BN;
    const int tid  = threadIdx.x;
    const int wave = tid >> 6;
    const int lane = tid & 63;
    const int wm = (wave >> 1) * 64;
    const int wn = (wave & 1) * 64;

    f32x4 acc[4][4] = {};

    for (int kk = 0; kk < D_IN; kk += BK) {
        __syncthreads();  // previous-iteration LDS reads done before overwrite
        #pragma unroll
        for (int i = 0; i < 4; ++i) {  // stage A tile: 128 rows x 64 k
            int rbase = i * 32 + wave * 8;
            int r = rbase + (lane >> 3);
            int gc = (lane & 7) ^ (r & 7);  // inverse-swizzled source chunk
            const unsigned short* g = A + (size_t)(M0 + r) * D_IN + kk + gc * 8;
            __builtin_amdgcn_global_load_lds(
                (const __attribute__((address_space(1))) void*)g,
                (__attribute__((address_space(3))) void*)(As + rbase * 64), 16, 0, 0);
        }
        #pragma unroll
        for (int i = 0; i < 4; ++i) {  // stage B tile: 128 cols x 64 k
            int rbase = i * 32 + wave * 8;
            int r = rbase + (lane >> 3);
            int gc = (lane & 7) ^ (r & 7);
            const unsigned short* g = B + (size_t)(N0 + r) * D_IN + kk + gc * 8;
            __builtin_amdgcn_global_load_lds(
                (const __attribute__((address_space(1))) void*)g,
                (__attribute__((address_space(3))) void*)(Bs + rbase * 64), 16, 0, 0);
        }
        __syncthreads();

        #pragma unroll
        for (int ks = 0; ks < 2; ++ks) {
            bf16x8 a[4], b[4];
            #pragma unroll
            for (int m = 0; m < 4; ++m) {
                int r = wm + m * 16 + (lane & 15);
                int lc = (ks * 4 + (lane >> 4)) ^ (r & 7);  // swizzled read chunk
                a[m] = *(const bf16x8*)(As + r * 64 + lc * 8);
            }
            #pragma unroll
            for (int n = 0; n < 4; ++n) {
                int c = wn + n * 16 + (lane & 15);
                int lc = (ks * 4 + (lane >> 4)) ^ (c & 7);
                b[n] = *(const bf16x8*)(Bs + c * 64 + lc * 8);
            }
            #pragma unroll
            for (int m = 0; m < 4; ++m)
                #pragma unroll
                for (int n = 0; n < 4; ++n)
                    acc[m][n] = __builtin_amdgcn_mfma_f32_16x16x32_bf16(
                        b[n], a[m], acc[m][n], 0, 0, 0);   // SWAPPED -> C^T regs
        }
    }

    // Swapped C/D layout: M = lane&15, N = (lane>>4)*4 + reg -> f32x4 NT store.
    #pragma unroll
    for (int m = 0; m < 4; ++m) {
        int row = M0 + wm + m * 16 + (lane & 15);
        if (row < M) {
            #pragma unroll
            for (int n = 0; n < 4; ++n) {
                int col = N0 + wn + n * 16 + (lane >> 4) * 4;
                __builtin_nontemporal_store(
                    acc[m][n], (f32x4*)(C + (size_t)row * D_OUT_T + col));
            }
        }
    }
}

extern "C" void kernel_launch(void* const* d_in, const int* in_sizes, int n_in,
                              void* d_out, int out_size, void* d_ws, size_t ws_size,
                              hipStream_t stream) {
    const float* h  = (const float*)d_in[0];
    const float* W  = (const float*)d_in[1];
    const int* erow = (const int*)d_in[2];
    const int* ecol = erow + N_EDGES;
    float* out = (float*)d_out;

    char* base = (char*)d_ws;
    size_t off = 0;
    auto alloc = [&](size_t b) {
        char* p = base + off;
        off += (b + 255) & ~(size_t)255;
        return p;
    };
    int* deg    = (int*)alloc((N_NODES + 1) * sizeof(int));  // [N] = global cursor
    int* start  = (int*)alloc(N_NODES * sizeof(int));
    int* rank   = (int*)alloc((size_t)N_EDGES * sizeof(int));
    int* colidx = (int*)alloc((size_t)N_EDGES * sizeof(int));
    unsigned short* WcT  = (unsigned short*)alloc((size_t)D_OUT_T * D_IN * 2);
    unsigned short* hagg = (unsigned short*)alloc((size_t)MPAD * D_IN * 2);
    int*   h8    = (int*)alloc((size_t)N_NODES * 64 * sizeof(int));  // 25.6MB
    float* scale = (float*)alloc((size_t)N_NODES * sizeof(float));
    bool use_h8 = (off <= ws_size);  // fall back to fp32 gather if ws too small

    hipMemsetAsync(deg, 0, (N_NODES + 1) * sizeof(int), stream);

    k_pre2<<<NB_DEG + NB_H8 + NB_WCT, 256, 0, stream>>>(
        erow, deg, rank, h, h8, scale, W, WcT, use_h8 ? 1 : 0);

    const int NB = (N_NODES + 255) / 256;  // 391
    k_scan<<<NB, 256, 0, stream>>>(deg, start, deg + N_NODES);

    k_fill<<<FILL_BLOCKS, 256, 0, stream>>>(erow, ecol, rank, start, colidx);

    if (use_h8)
        k_agg<true><<<(N_NODES + 3) / 4, 256, 0, stream>>>(
            h8, scale, start, deg, colidx, hagg);
    else
        k_agg<false><<<(N_NODES + 3) / 4, 256, 0, stream>>>(
            h, scale, start, deg, colidx, hagg);

    k_gemm<<<MPAD / BM * 4, 256, 0, stream>>>(hagg, WcT, out, N_NODES);
}